// Round 1
// baseline (307.033 us; speedup 1.0000x reference)
//
#include <hip/hip_runtime.h>
#include <hip/hip_bf16.h>

typedef __bf16 v8bf __attribute__((ext_vector_type(8)));
typedef __bf16 v4bf __attribute__((ext_vector_type(4)));
typedef float  f32x4 __attribute__((ext_vector_type(4)));

#define NTOK 1024
#define HDIM 1024
#define FDIM 3584
#define NEXP 8
#define NPAIR 2048

// workspace layout (bytes)
#define OFF_COUNTS   0                      // 8 int  (zeroed each launch)
#define OFF_OFFSETS  64                     // 8 int
#define OFF_TOKIDX   128                    // 2048 int
#define OFF_TOKWT    (128 + 4*NPAIR)        // 2048 float
#define OFF_PAIRTOK  (OFF_TOKWT + 4*NPAIR)  // 2048+128 int
#define OFF_PAIRWT   (OFF_PAIRTOK + 4*(NPAIR+128))
#define OFF_SLOTOF   (OFF_PAIRWT + 4*(NPAIR+128))
#define OFF_ACT      65536                          // bf16 [2048][3584]
#define OFF_Y        (OFF_ACT + 2ull*NPAIR*FDIM)    // f32  [2048][1024]

static __device__ inline v4bf cvt4(float4 f) {
    v4bf r;
    r[0] = (__bf16)f.x; r[1] = (__bf16)f.y; r[2] = (__bf16)f.z; r[3] = (__bf16)f.w;
    return r;
}

// ---------------- router: fp32 logits, softmax-free top-2 + renorm ----------------
__global__ __launch_bounds__(256) void moe_router(
    const float* __restrict__ x, const float* __restrict__ gw,
    float* __restrict__ logits, int* __restrict__ counts,
    int* __restrict__ tok_idx, float* __restrict__ tok_wt)
{
    __shared__ float red[NEXP][256];
    const int t = blockIdx.x;
    const int tid = threadIdx.x;
    float acc[NEXP];
#pragma unroll
    for (int e = 0; e < NEXP; ++e) acc[e] = 0.f;
    const float* xr = x + (size_t)t * HDIM;
    for (int h = tid; h < HDIM; h += 256) {
        float xv = xr[h];
#pragma unroll
        for (int e = 0; e < NEXP; ++e) acc[e] += xv * gw[e * HDIM + h];
    }
#pragma unroll
    for (int e = 0; e < NEXP; ++e) red[e][tid] = acc[e];
    __syncthreads();
    for (int s = 128; s > 0; s >>= 1) {
        if (tid < s) {
#pragma unroll
            for (int e = 0; e < NEXP; ++e) red[e][tid] += red[e][tid + s];
        }
        __syncthreads();
    }
    if (tid == 0) {
        float l[NEXP];
#pragma unroll
        for (int e = 0; e < NEXP; ++e) { l[e] = red[e][0]; logits[t * NEXP + e] = l[e]; }
        int i0 = 0;
#pragma unroll
        for (int e = 1; e < NEXP; ++e) if (l[e] > l[i0]) i0 = e;   // first max (jax tie-break)
        int i1 = (i0 == 0) ? 1 : 0;
#pragma unroll
        for (int e = 0; e < NEXP; ++e) if (e != i0 && l[e] > l[i1]) i1 = e;
        // renormalized top-2 softmax == sigmoid of logit gap
        float w0 = 1.f / (1.f + expf(l[i1] - l[i0]));
        float w1 = 1.f - w0;
        tok_idx[2 * t] = i0; tok_idx[2 * t + 1] = i1;
        tok_wt[2 * t] = w0;  tok_wt[2 * t + 1] = w1;
        atomicAdd(&counts[i0], 1);
        atomicAdd(&counts[i1], 1);
    }
}

// ---------------- scatter: build per-expert token lists (single block) ----------------
__global__ void moe_scatter(const int* __restrict__ counts, const int* __restrict__ tok_idx,
                            const float* __restrict__ tok_wt, int* __restrict__ offsets,
                            int* __restrict__ pair_token, float* __restrict__ pair_wt,
                            int* __restrict__ slot_of)
{
    __shared__ int cur[NEXP];
    const int tid = threadIdx.x;
    if (tid == 0) {
        int run = 0;
        for (int e = 0; e < NEXP; ++e) { offsets[e] = run; cur[e] = run; run += counts[e]; }
    }
    __syncthreads();
    for (int p = tid; p < 2 * NTOK; p += blockDim.x) {
        int e = tok_idx[p];
        int s = atomicAdd(&cur[e], 1);
        pair_token[s] = p >> 1;
        pair_wt[s] = tok_wt[p];
        slot_of[p] = s;     // slot permutation varies with atomics, values don't
    }
}

// ---------------- GEMM1 fused: h1 = X@w1^T, h3 = X@w3^T, act = silu(h1)*h3 ----------------
__global__ __launch_bounds__(256, 2) void moe_gemm1(
    const float* __restrict__ x, const float* __restrict__ w1g,
    const float* __restrict__ w3g, const int* __restrict__ counts,
    const int* __restrict__ offsets, const int* __restrict__ pair_token,
    __bf16* __restrict__ act)
{
    const int e = blockIdx.z;
    const int Me = counts[e];
    const int m0 = blockIdx.y * 128;
    if (m0 >= Me) return;
    const int rows = min(128, Me - m0);
    const int slot0 = offsets[e] + m0;
    const int n0 = blockIdx.x * 128;

    __shared__ __align__(16) __bf16 As[128 * 32];
    __shared__ __align__(16) __bf16 B1s[128 * 32];
    __shared__ __align__(16) __bf16 B3s[128 * 32];

    const int tid = threadIdx.x;
    const int lane = tid & 63;
    const int wv = tid >> 6;
    const int wm = (wv >> 1) * 64;
    const int wn = (wv & 1) * 64;
    const int lr = lane & 15;
    const int lk = (lane >> 4) * 8;

    f32x4 acc1[4][4], acc3[4][4];
#pragma unroll
    for (int i = 0; i < 4; ++i)
#pragma unroll
        for (int j = 0; j < 4; ++j) {
            acc1[i][j] = (f32x4){0.f, 0.f, 0.f, 0.f};
            acc3[i][j] = (f32x4){0.f, 0.f, 0.f, 0.f};
        }

    const ptrdiff_t d31 = w3g - w1g;   // uniform
    const float* aptr[4];
    const float* b1p[4];
    int wof[4];
#pragma unroll
    for (int i = 0; i < 4; ++i) {
        int flat = tid + i * 256;
        int r = flat >> 3;
        int c = (flat & 7) * 4;
        int rr = (r < rows) ? r : 0;
        aptr[i] = x + (size_t)pair_token[slot0 + rr] * HDIM + c;
        b1p[i]  = w1g + ((size_t)e * FDIM + n0 + r) * HDIM + c;
        wof[i]  = r * 32 + c;
    }

    for (int k0 = 0; k0 < HDIM; k0 += 32) {
        float4 av[4], b1v[4], b3v[4];
#pragma unroll
        for (int i = 0; i < 4; ++i) {
            av[i]  = *(const float4*)(aptr[i] + k0);
            b1v[i] = *(const float4*)(b1p[i] + k0);
            b3v[i] = *(const float4*)(b1p[i] + d31 + k0);
        }
#pragma unroll
        for (int i = 0; i < 4; ++i) {
            *(v4bf*)&As[wof[i]]  = cvt4(av[i]);
            *(v4bf*)&B1s[wof[i]] = cvt4(b1v[i]);
            *(v4bf*)&B3s[wof[i]] = cvt4(b3v[i]);
        }
        __syncthreads();
        v8bf af[4], b1f[4], b3f[4];
#pragma unroll
        for (int i = 0; i < 4; ++i) {
            af[i]  = *(const v8bf*)&As[(wm + i * 16 + lr) * 32 + lk];
            b1f[i] = *(const v8bf*)&B1s[(wn + i * 16 + lr) * 32 + lk];
            b3f[i] = *(const v8bf*)&B3s[(wn + i * 16 + lr) * 32 + lk];
        }
#pragma unroll
        for (int mi = 0; mi < 4; ++mi)
#pragma unroll
            for (int ni = 0; ni < 4; ++ni) {
                acc1[mi][ni] = __builtin_amdgcn_mfma_f32_16x16x32_bf16(af[mi], b1f[ni], acc1[mi][ni], 0, 0, 0);
                acc3[mi][ni] = __builtin_amdgcn_mfma_f32_16x16x32_bf16(af[mi], b3f[ni], acc3[mi][ni], 0, 0, 0);
            }
        __syncthreads();
    }

    const int rj = (lane >> 4) * 4;
#pragma unroll
    for (int mi = 0; mi < 4; ++mi) {
#pragma unroll
        for (int j = 0; j < 4; ++j) {
            int rm = wm + mi * 16 + rj + j;
            if (rm < rows) {
                size_t rowoff = (size_t)(slot0 + rm) * FDIM + n0 + wn;
#pragma unroll
                for (int ni = 0; ni < 4; ++ni) {
                    float h1 = acc1[mi][ni][j];
                    float h3 = acc3[mi][ni][j];
                    float sv = (h1 / (1.f + __expf(-h1))) * h3;  // silu(h1)*h3
                    act[rowoff + ni * 16 + lr] = (__bf16)sv;
                }
            }
        }
    }
}

// ---------------- GEMM2: y = act @ w2^T ----------------
__global__ __launch_bounds__(256, 2) void moe_gemm2(
    const __bf16* __restrict__ act, const float* __restrict__ w2g,
    const int* __restrict__ counts, const int* __restrict__ offsets,
    float* __restrict__ y)
{
    const int e = blockIdx.z;
    const int Me = counts[e];
    const int m0 = blockIdx.y * 128;
    if (m0 >= Me) return;
    const int rows = min(128, Me - m0);
    const int slot0 = offsets[e] + m0;
    const int n0 = blockIdx.x * 128;

    __shared__ __align__(16) __bf16 As[128 * 32];
    __shared__ __align__(16) __bf16 Bs[128 * 32];

    const int tid = threadIdx.x;
    const int lane = tid & 63;
    const int wv = tid >> 6;
    const int wm = (wv >> 1) * 64;
    const int wn = (wv & 1) * 64;
    const int lr = lane & 15;
    const int lk = (lane >> 4) * 8;

    f32x4 acc[4][4];
#pragma unroll
    for (int i = 0; i < 4; ++i)
#pragma unroll
        for (int j = 0; j < 4; ++j) acc[i][j] = (f32x4){0.f, 0.f, 0.f, 0.f};

    const __bf16* ap[2];
    int awof[2];
#pragma unroll
    for (int i = 0; i < 2; ++i) {
        int flat = tid + i * 256;
        int r = flat >> 2;
        int c = (flat & 3) * 8;
        int rr = (r < rows) ? r : 0;
        ap[i]   = act + (size_t)(slot0 + rr) * FDIM + c;
        awof[i] = r * 32 + c;
    }
    const float* bp[4];
    int bwof[4];
#pragma unroll
    for (int i = 0; i < 4; ++i) {
        int flat = tid + i * 256;
        int r = flat >> 3;
        int c = (flat & 7) * 4;
        bp[i]   = w2g + ((size_t)e * HDIM + n0 + r) * FDIM + c;
        bwof[i] = r * 32 + c;
    }

    for (int k0 = 0; k0 < FDIM; k0 += 32) {
        v8bf a8[2];
        float4 bv[4];
#pragma unroll
        for (int i = 0; i < 2; ++i) a8[i] = *(const v8bf*)(ap[i] + k0);
#pragma unroll
        for (int i = 0; i < 4; ++i) bv[i] = *(const float4*)(bp[i] + k0);
#pragma unroll
        for (int i = 0; i < 2; ++i) *(v8bf*)&As[awof[i]] = a8[i];
#pragma unroll
        for (int i = 0; i < 4; ++i) *(v4bf*)&Bs[bwof[i]] = cvt4(bv[i]);
        __syncthreads();
        v8bf af[4], bf[4];
#pragma unroll
        for (int i = 0; i < 4; ++i) {
            af[i] = *(const v8bf*)&As[(wm + i * 16 + lr) * 32 + lk];
            bf[i] = *(const v8bf*)&Bs[(wn + i * 16 + lr) * 32 + lk];
        }
#pragma unroll
        for (int mi = 0; mi < 4; ++mi)
#pragma unroll
            for (int ni = 0; ni < 4; ++ni)
                acc[mi][ni] = __builtin_amdgcn_mfma_f32_16x16x32_bf16(af[mi], bf[ni], acc[mi][ni], 0, 0, 0);
        __syncthreads();
    }

    const int rj = (lane >> 4) * 4;
#pragma unroll
    for (int mi = 0; mi < 4; ++mi) {
#pragma unroll
        for (int j = 0; j < 4; ++j) {
            int rm = wm + mi * 16 + rj + j;
            if (rm < rows) {
                size_t rowoff = (size_t)(slot0 + rm) * HDIM + n0 + wn;
#pragma unroll
                for (int ni = 0; ni < 4; ++ni)
                    y[rowoff + ni * 16 + lr] = acc[mi][ni][j];
            }
        }
    }
}

// ---------------- combine: out[t] = w0*y[slot0] + w1*y[slot1] ----------------
__global__ __launch_bounds__(256) void moe_combine(
    const float* __restrict__ y, const int* __restrict__ slot_of,
    const float* __restrict__ pair_wt, float* __restrict__ out)
{
    const int t = blockIdx.x;
    const int tid = threadIdx.x;
    const int s0 = slot_of[2 * t];
    const int s1 = slot_of[2 * t + 1];
    const float w0 = pair_wt[s0];
    const float w1 = pair_wt[s1];
    const float4 a = *(const float4*)(y + (size_t)s0 * HDIM + tid * 4);
    const float4 b = *(const float4*)(y + (size_t)s1 * HDIM + tid * 4);
    float4 o;
    o.x = w0 * a.x + w1 * b.x;
    o.y = w0 * a.y + w1 * b.y;
    o.z = w0 * a.z + w1 * b.z;
    o.w = w0 * a.w + w1 * b.w;
    *(float4*)(out + (size_t)t * HDIM + tid * 4) = o;
}

extern "C" void kernel_launch(void* const* d_in, const int* in_sizes, int n_in,
                              void* d_out, int out_size, void* d_ws, size_t ws_size,
                              hipStream_t stream) {
    const float* x   = (const float*)d_in[0];   // [2,512,1024]
    const float* gw  = (const float*)d_in[1];   // [8,1024]
    const float* w1  = (const float*)d_in[2];   // [8,3584,1024]
    const float* w2  = (const float*)d_in[3];   // [8,1024,3584]
    const float* w3  = (const float*)d_in[4];   // [8,3584,1024]

    float* out    = (float*)d_out;              // [1024,1024]
    float* logits = out + (size_t)NTOK * HDIM;  // [1024,8]

    char* ws = (char*)d_ws;
    int*    counts     = (int*)(ws + OFF_COUNTS);
    int*    offsets    = (int*)(ws + OFF_OFFSETS);
    int*    tok_idx    = (int*)(ws + OFF_TOKIDX);
    float*  tok_wt     = (float*)(ws + OFF_TOKWT);
    int*    pair_token = (int*)(ws + OFF_PAIRTOK);
    float*  pair_wt    = (float*)(ws + OFF_PAIRWT);
    int*    slot_of    = (int*)(ws + OFF_SLOTOF);
    __bf16* act        = (__bf16*)(ws + OFF_ACT);
    float*  yb         = (float*)(ws + OFF_Y);

    hipMemsetAsync(counts, 0, 64, stream);

    moe_router<<<dim3(NTOK), dim3(256), 0, stream>>>(x, gw, logits, counts, tok_idx, tok_wt);
    moe_scatter<<<dim3(1), dim3(256), 0, stream>>>(counts, tok_idx, tok_wt, offsets,
                                                   pair_token, pair_wt, slot_of);
    moe_gemm1<<<dim3(FDIM / 128, 8, NEXP), dim3(256), 0, stream>>>(
        x, w1, w3, counts, offsets, pair_token, act);
    moe_gemm2<<<dim3(HDIM / 128, 8, NEXP), dim3(256), 0, stream>>>(
        act, w2, counts, offsets, yb);
    moe_combine<<<dim3(NTOK), dim3(256), 0, stream>>>(yb, slot_of, pair_wt, out);
}

// Round 2
// 234.560 us; speedup vs baseline: 1.3090x; 1.3090x over previous
//
#include <hip/hip_runtime.h>
#include <hip/hip_bf16.h>

typedef __bf16 v8bf __attribute__((ext_vector_type(8)));
typedef __bf16 v4bf __attribute__((ext_vector_type(4)));
typedef float  f32x4 __attribute__((ext_vector_type(4)));

#define NTOK 1024
#define HDIM 1024
#define FDIM 3584
#define NEXP 8
#define NPAIR 2048
#define MAXTILES 24

// workspace layout (bytes)
#define OFF_COUNTS   0
#define OFF_OFFSETS  64
#define OFF_NTILES   128
#define OFF_TILE_E   192
#define OFF_TILE_M   320
#define OFF_TOKIDX   1024
#define OFF_TOKWT    (1024 + 4*NPAIR)
#define OFF_PAIRTOK  (OFF_TOKWT + 4*NPAIR)
#define OFF_PAIRWT   (OFF_PAIRTOK + 4*NPAIR)
#define OFF_SLOTOF   (OFF_PAIRWT + 4*NPAIR)
#define OFF_ACT      65536                          // bf16 [2048][3584]
#define OFF_Y        (OFF_ACT + 2ull*NPAIR*FDIM)    // f32  [2048][1024]

static __device__ inline v4bf cvt4(float4 f) {
    v4bf r;
    r[0] = (__bf16)f.x; r[1] = (__bf16)f.y; r[2] = (__bf16)f.z; r[3] = (__bf16)f.w;
    return r;
}

#define BAR() do { asm volatile("s_waitcnt lgkmcnt(0)" ::: "memory"); \
                   __builtin_amdgcn_s_barrier(); } while (0)

// ---------------- router: wave-per-token, fp32 logits, top-2 + renorm ----------------
__global__ __launch_bounds__(256) void moe_router(
    const float* __restrict__ x, const float* __restrict__ gw,
    float* __restrict__ logits, int* __restrict__ counts,
    int* __restrict__ tok_idx, float* __restrict__ tok_wt)
{
    const int lane = threadIdx.x & 63;
    const int wv = threadIdx.x >> 6;
    const int t = blockIdx.x * 4 + wv;
    const float* xr = x + (size_t)t * HDIM;

    float acc[NEXP];
#pragma unroll
    for (int e = 0; e < NEXP; ++e) acc[e] = 0.f;
#pragma unroll
    for (int j = 0; j < 4; ++j) {
        int h = lane * 4 + j * 256;
        float4 xv = *(const float4*)(xr + h);
#pragma unroll
        for (int e = 0; e < NEXP; ++e) {
            float4 g = *(const float4*)(gw + e * HDIM + h);
            acc[e] += xv.x * g.x + xv.y * g.y + xv.z * g.z + xv.w * g.w;
        }
    }
#pragma unroll
    for (int e = 0; e < NEXP; ++e) {
#pragma unroll
        for (int s = 32; s > 0; s >>= 1) acc[e] += __shfl_xor(acc[e], s);
    }
    if (lane == 0) {
#pragma unroll
        for (int e = 0; e < NEXP; ++e) logits[t * NEXP + e] = acc[e];
        int i0 = 0;
#pragma unroll
        for (int e = 1; e < NEXP; ++e) if (acc[e] > acc[i0]) i0 = e;
        int i1 = (i0 == 0) ? 1 : 0;
#pragma unroll
        for (int e = 0; e < NEXP; ++e) if (e != i0 && acc[e] > acc[i1]) i1 = e;
        float w0 = 1.f / (1.f + expf(acc[i1] - acc[i0]));
        float w1 = 1.f - w0;
        tok_idx[2 * t] = i0; tok_idx[2 * t + 1] = i1;
        tok_wt[2 * t] = w0;  tok_wt[2 * t + 1] = w1;
        atomicAdd(&counts[i0], 1);
        atomicAdd(&counts[i1], 1);
    }
}

// ---------------- scatter: per-expert token lists + tile list (single block) ----------------
__global__ void moe_scatter(const int* __restrict__ counts, const int* __restrict__ tok_idx,
                            const float* __restrict__ tok_wt, int* __restrict__ offsets,
                            int* __restrict__ pair_token, float* __restrict__ pair_wt,
                            int* __restrict__ slot_of, int* __restrict__ tile_e,
                            int* __restrict__ tile_m, int* __restrict__ ntiles)
{
    __shared__ int cur[NEXP];
    const int tid = threadIdx.x;
    if (tid == 0) {
        int run = 0, nt = 0;
        for (int e = 0; e < NEXP; ++e) {
            offsets[e] = run; cur[e] = run;
            for (int m0 = 0; m0 < counts[e]; m0 += 128) {
                tile_e[nt] = e; tile_m[nt] = m0; ++nt;
            }
            run += counts[e];
        }
        *ntiles = nt;
    }
    __syncthreads();
    for (int p = tid; p < 2 * NTOK; p += blockDim.x) {
        int e = tok_idx[p];
        int s = atomicAdd(&cur[e], 1);
        pair_token[s] = p >> 1;
        pair_wt[s] = tok_wt[p];
        slot_of[p] = s;
    }
}

// ---------------- GEMM1 fused: act = silu(X@w1^T) * (X@w3^T), double-buffered ----------------
__global__ __launch_bounds__(256, 2) void moe_gemm1(
    const float* __restrict__ x, const float* __restrict__ w1g,
    const float* __restrict__ w3g, const int* __restrict__ counts,
    const int* __restrict__ offsets, const int* __restrict__ pair_token,
    const int* __restrict__ tile_e, const int* __restrict__ tile_m,
    const int* __restrict__ ntiles,
    __bf16* __restrict__ act)
{
    const int ty = blockIdx.y;
    if (ty >= *ntiles) return;
    const int e = tile_e[ty];
    const int m0 = tile_m[ty];
    const int Me = counts[e];
    const int rows = min(128, Me - m0);
    const int slot0 = offsets[e] + m0;
    const int n0 = blockIdx.x * 128;

    __shared__ __align__(16) __bf16 As[2][128 * 32];
    __shared__ __align__(16) __bf16 B1s[2][128 * 32];
    __shared__ __align__(16) __bf16 B3s[2][128 * 32];

    const int tid = threadIdx.x;
    const int lane = tid & 63;
    const int wv = tid >> 6;
    const int wm = (wv >> 1) * 64;
    const int wn = (wv & 1) * 64;
    const int lr = lane & 15;
    const int lk = (lane >> 4) * 8;

    f32x4 acc1[4][4], acc3[4][4];
#pragma unroll
    for (int i = 0; i < 4; ++i)
#pragma unroll
        for (int j = 0; j < 4; ++j) {
            acc1[i][j] = (f32x4){0.f, 0.f, 0.f, 0.f};
            acc3[i][j] = (f32x4){0.f, 0.f, 0.f, 0.f};
        }

    const ptrdiff_t d31 = w3g - w1g;
    const float* aptr[4];
    const float* b1p[4];
    int wof[4];
#pragma unroll
    for (int i = 0; i < 4; ++i) {
        int flat = tid + i * 256;
        int r = flat >> 3;
        int c = (flat & 7) * 4;
        int rr = (r < rows) ? r : 0;
        aptr[i] = x + (size_t)pair_token[slot0 + rr] * HDIM + c;
        b1p[i]  = w1g + ((size_t)e * FDIM + n0 + r) * HDIM + c;
        wof[i]  = r * 32 + c;
    }

    float4 av[4], b1v[4], b3v[4];
#define LOADK1(K0) do { _Pragma("unroll") \
    for (int i = 0; i < 4; ++i) { \
        av[i]  = *(const float4*)(aptr[i] + (K0)); \
        b1v[i] = *(const float4*)(b1p[i] + (K0)); \
        b3v[i] = *(const float4*)(b1p[i] + d31 + (K0)); \
    } } while (0)

    LOADK1(0);
    int cur = 0;
    for (int k0 = 0; k0 < HDIM; k0 += 32) {
#pragma unroll
        for (int i = 0; i < 4; ++i) {
            *(v4bf*)&As[cur][wof[i]]  = cvt4(av[i]);
            *(v4bf*)&B1s[cur][wof[i]] = cvt4(b1v[i]);
            *(v4bf*)&B3s[cur][wof[i]] = cvt4(b3v[i]);
        }
        if (k0 + 32 < HDIM) LOADK1(k0 + 32);   // prefetch stays in flight across barrier
        BAR();
        v8bf af[4], b1f[4], b3f[4];
#pragma unroll
        for (int i = 0; i < 4; ++i) {
            af[i]  = *(const v8bf*)&As[cur][(wm + i * 16 + lr) * 32 + lk];
            b1f[i] = *(const v8bf*)&B1s[cur][(wn + i * 16 + lr) * 32 + lk];
            b3f[i] = *(const v8bf*)&B3s[cur][(wn + i * 16 + lr) * 32 + lk];
        }
#pragma unroll
        for (int mi = 0; mi < 4; ++mi)
#pragma unroll
            for (int ni = 0; ni < 4; ++ni) {
                acc1[mi][ni] = __builtin_amdgcn_mfma_f32_16x16x32_bf16(af[mi], b1f[ni], acc1[mi][ni], 0, 0, 0);
                acc3[mi][ni] = __builtin_amdgcn_mfma_f32_16x16x32_bf16(af[mi], b3f[ni], acc3[mi][ni], 0, 0, 0);
            }
        cur ^= 1;
    }

    const int rj = (lane >> 4) * 4;
#pragma unroll
    for (int mi = 0; mi < 4; ++mi) {
#pragma unroll
        for (int j = 0; j < 4; ++j) {
            int rm = wm + mi * 16 + rj + j;
            if (rm < rows) {
                size_t rowoff = (size_t)(slot0 + rm) * FDIM + n0 + wn;
#pragma unroll
                for (int ni = 0; ni < 4; ++ni) {
                    float h1 = acc1[mi][ni][j];
                    float h3 = acc3[mi][ni][j];
                    float sv = (h1 / (1.f + __expf(-h1))) * h3;
                    act[rowoff + ni * 16 + lr] = (__bf16)sv;
                }
            }
        }
    }
}

// ---------------- GEMM2: y = act @ w2^T, tile 128x64, double-buffered ----------------
__global__ __launch_bounds__(256, 2) void moe_gemm2(
    const __bf16* __restrict__ act, const float* __restrict__ w2g,
    const int* __restrict__ counts, const int* __restrict__ offsets,
    const int* __restrict__ tile_e, const int* __restrict__ tile_m,
    const int* __restrict__ ntiles,
    float* __restrict__ y)
{
    const int ty = blockIdx.y;
    if (ty >= *ntiles) return;
    const int e = tile_e[ty];
    const int m0 = tile_m[ty];
    const int Me = counts[e];
    const int rows = min(128, Me - m0);
    const int slot0 = offsets[e] + m0;
    const int n0 = blockIdx.x * 64;

    __shared__ __align__(16) __bf16 As[2][128 * 32];
    __shared__ __align__(16) __bf16 Bs[2][64 * 32];

    const int tid = threadIdx.x;
    const int lane = tid & 63;
    const int wv = tid >> 6;
    const int wm = (wv >> 1) * 64;
    const int wn = (wv & 1) * 32;
    const int lr = lane & 15;
    const int lk = (lane >> 4) * 8;

    f32x4 acc[4][2];
#pragma unroll
    for (int i = 0; i < 4; ++i)
#pragma unroll
        for (int j = 0; j < 2; ++j) acc[i][j] = (f32x4){0.f, 0.f, 0.f, 0.f};

    const __bf16* ap[2];
    int awof[2];
#pragma unroll
    for (int i = 0; i < 2; ++i) {
        int flat = tid + i * 256;
        int r = flat >> 2;
        int c = (flat & 3) * 8;
        int rr = (r < rows) ? r : 0;
        ap[i]   = act + (size_t)(slot0 + rr) * FDIM + c;
        awof[i] = r * 32 + c;
    }
    const float* bp[2];
    int bwof[2];
#pragma unroll
    for (int i = 0; i < 2; ++i) {
        int flat = tid + i * 256;
        int r = flat >> 3;
        int c = (flat & 7) * 4;
        bp[i]   = w2g + ((size_t)e * HDIM + n0 + r) * FDIM + c;
        bwof[i] = r * 32 + c;
    }

    v8bf a8[2];
    float4 bv[2];
#define LOADK2(K0) do { _Pragma("unroll") \
    for (int i = 0; i < 2; ++i) { \
        a8[i] = *(const v8bf*)(ap[i] + (K0)); \
        bv[i] = *(const float4*)(bp[i] + (K0)); \
    } } while (0)

    LOADK2(0);
    int cur = 0;
    for (int k0 = 0; k0 < FDIM; k0 += 32) {
#pragma unroll
        for (int i = 0; i < 2; ++i) {
            *(v8bf*)&As[cur][awof[i]] = a8[i];
            *(v4bf*)&Bs[cur][bwof[i]] = cvt4(bv[i]);
        }
        if (k0 + 32 < FDIM) LOADK2(k0 + 32);
        BAR();
        v8bf af[4], bf[2];
#pragma unroll
        for (int i = 0; i < 4; ++i)
            af[i] = *(const v8bf*)&As[cur][(wm + i * 16 + lr) * 32 + lk];
#pragma unroll
        for (int i = 0; i < 2; ++i)
            bf[i] = *(const v8bf*)&Bs[cur][(wn + i * 16 + lr) * 32 + lk];
#pragma unroll
        for (int mi = 0; mi < 4; ++mi)
#pragma unroll
            for (int ni = 0; ni < 2; ++ni)
                acc[mi][ni] = __builtin_amdgcn_mfma_f32_16x16x32_bf16(af[mi], bf[ni], acc[mi][ni], 0, 0, 0);
        cur ^= 1;
    }

    const int rj = (lane >> 4) * 4;
#pragma unroll
    for (int mi = 0; mi < 4; ++mi) {
#pragma unroll
        for (int j = 0; j < 4; ++j) {
            int rm = wm + mi * 16 + rj + j;
            if (rm < rows) {
                size_t rowoff = (size_t)(slot0 + rm) * HDIM + n0 + wn;
#pragma unroll
                for (int ni = 0; ni < 2; ++ni)
                    y[rowoff + ni * 16 + lr] = acc[mi][ni][j];
            }
        }
    }
}

// ---------------- combine: out[t] = w0*y[slot0] + w1*y[slot1] ----------------
__global__ __launch_bounds__(256) void moe_combine(
    const float* __restrict__ y, const int* __restrict__ slot_of,
    const float* __restrict__ pair_wt, float* __restrict__ out)
{
    const int t = blockIdx.x;
    const int tid = threadIdx.x;
    const int s0 = slot_of[2 * t];
    const int s1 = slot_of[2 * t + 1];
    const float w0 = pair_wt[s0];
    const float w1 = pair_wt[s1];
    const float4 a = *(const float4*)(y + (size_t)s0 * HDIM + tid * 4);
    const float4 b = *(const float4*)(y + (size_t)s1 * HDIM + tid * 4);
    float4 o;
    o.x = w0 * a.x + w1 * b.x;
    o.y = w0 * a.y + w1 * b.y;
    o.z = w0 * a.z + w1 * b.z;
    o.w = w0 * a.w + w1 * b.w;
    *(float4*)(out + (size_t)t * HDIM + tid * 4) = o;
}

extern "C" void kernel_launch(void* const* d_in, const int* in_sizes, int n_in,
                              void* d_out, int out_size, void* d_ws, size_t ws_size,
                              hipStream_t stream) {
    const float* x   = (const float*)d_in[0];
    const float* gw  = (const float*)d_in[1];
    const float* w1  = (const float*)d_in[2];
    const float* w2  = (const float*)d_in[3];
    const float* w3  = (const float*)d_in[4];

    float* out    = (float*)d_out;
    float* logits = out + (size_t)NTOK * HDIM;

    char* ws = (char*)d_ws;
    int*    counts     = (int*)(ws + OFF_COUNTS);
    int*    offsets    = (int*)(ws + OFF_OFFSETS);
    int*    ntiles     = (int*)(ws + OFF_NTILES);
    int*    tile_e     = (int*)(ws + OFF_TILE_E);
    int*    tile_m     = (int*)(ws + OFF_TILE_M);
    int*    tok_idx    = (int*)(ws + OFF_TOKIDX);
    float*  tok_wt     = (float*)(ws + OFF_TOKWT);
    int*    pair_token = (int*)(ws + OFF_PAIRTOK);
    float*  pair_wt    = (float*)(ws + OFF_PAIRWT);
    int*    slot_of    = (int*)(ws + OFF_SLOTOF);
    __bf16* act        = (__bf16*)(ws + OFF_ACT);
    float*  yb         = (float*)(ws + OFF_Y);

    hipMemsetAsync(counts, 0, 64, stream);

    moe_router<<<dim3(NTOK / 4), dim3(256), 0, stream>>>(x, gw, logits, counts, tok_idx, tok_wt);
    moe_scatter<<<dim3(1), dim3(256), 0, stream>>>(counts, tok_idx, tok_wt, offsets,
                                                   pair_token, pair_wt, slot_of,
                                                   tile_e, tile_m, ntiles);
    moe_gemm1<<<dim3(FDIM / 128, MAXTILES), dim3(256), 0, stream>>>(
        x, w1, w3, counts, offsets, pair_token, tile_e, tile_m, ntiles, act);
    moe_gemm2<<<dim3(HDIM / 64, MAXTILES), dim3(256), 0, stream>>>(
        act, w2, counts, offsets, tile_e, tile_m, ntiles, yb);
    moe_combine<<<dim3(NTOK), dim3(256), 0, stream>>>(yb, slot_of, pair_wt, out);
}

// Round 3
// 210.382 us; speedup vs baseline: 1.4594x; 1.1149x over previous
//
#include <hip/hip_runtime.h>
#include <hip/hip_bf16.h>

typedef __bf16 v8bf __attribute__((ext_vector_type(8)));
typedef __bf16 v4bf __attribute__((ext_vector_type(4)));
typedef float  f32x4 __attribute__((ext_vector_type(4)));

#define NTOK 1024
#define HDIM 1024
#define FDIM 3584
#define NEXP 8
#define NPAIR 2048
#define MAXT1 24
#define MAXT2 40

// workspace layout (bytes)
#define OFF_COUNTS   0
#define OFF_OFFSETS  64
#define OFF_NT1      128
#define OFF_NT2      132
#define OFF_T1E      192
#define OFF_T1M      320
#define OFF_T2E      448
#define OFF_T2M      640
#define OFF_TOKIDX   1024
#define OFF_TOKWT    (1024 + 4*NPAIR)
#define OFF_PAIRTOK  (OFF_TOKWT + 4*NPAIR)
#define OFF_PAIRWT   (OFF_PAIRTOK + 4*NPAIR)
#define OFF_SLOTOF   (OFF_PAIRWT + 4*NPAIR)
#define OFF_ACT      65536                          // bf16 [2048][3584]
#define OFF_Y        (OFF_ACT + 2ull*NPAIR*FDIM)    // f32  [2048][1024]

static __device__ inline v4bf cvt4(float4 f) {
    v4bf r;
    r[0] = (__bf16)f.x; r[1] = (__bf16)f.y; r[2] = (__bf16)f.z; r[3] = (__bf16)f.w;
    return r;
}

#define BAR() do { asm volatile("s_waitcnt lgkmcnt(0)" ::: "memory"); \
                   __builtin_amdgcn_s_barrier(); } while (0)

// ---------------- router ----------------
__global__ __launch_bounds__(256) void moe_router(
    const float* __restrict__ x, const float* __restrict__ gw,
    float* __restrict__ logits, int* __restrict__ counts,
    int* __restrict__ tok_idx, float* __restrict__ tok_wt)
{
    const int lane = threadIdx.x & 63;
    const int wv = threadIdx.x >> 6;
    const int t = blockIdx.x * 4 + wv;
    const float* xr = x + (size_t)t * HDIM;

    float acc[NEXP];
#pragma unroll
    for (int e = 0; e < NEXP; ++e) acc[e] = 0.f;
#pragma unroll
    for (int j = 0; j < 4; ++j) {
        int h = lane * 4 + j * 256;
        float4 xv = *(const float4*)(xr + h);
#pragma unroll
        for (int e = 0; e < NEXP; ++e) {
            float4 g = *(const float4*)(gw + e * HDIM + h);
            acc[e] += xv.x * g.x + xv.y * g.y + xv.z * g.z + xv.w * g.w;
        }
    }
#pragma unroll
    for (int e = 0; e < NEXP; ++e) {
#pragma unroll
        for (int s = 32; s > 0; s >>= 1) acc[e] += __shfl_xor(acc[e], s);
    }
    if (lane == 0) {
#pragma unroll
        for (int e = 0; e < NEXP; ++e) logits[t * NEXP + e] = acc[e];
        int i0 = 0;
#pragma unroll
        for (int e = 1; e < NEXP; ++e) if (acc[e] > acc[i0]) i0 = e;
        int i1 = (i0 == 0) ? 1 : 0;
#pragma unroll
        for (int e = 0; e < NEXP; ++e) if (e != i0 && acc[e] > acc[i1]) i1 = e;
        float w0 = 1.f / (1.f + expf(acc[i1] - acc[i0]));
        float w1 = 1.f - w0;
        tok_idx[2 * t] = i0; tok_idx[2 * t + 1] = i1;
        tok_wt[2 * t] = w0;  tok_wt[2 * t + 1] = w1;
        atomicAdd(&counts[i0], 1);
        atomicAdd(&counts[i1], 1);
    }
}

// ---------------- scatter + tile lists ----------------
__global__ void moe_scatter(const int* __restrict__ counts, const int* __restrict__ tok_idx,
                            const float* __restrict__ tok_wt, int* __restrict__ offsets,
                            int* __restrict__ pair_token, float* __restrict__ pair_wt,
                            int* __restrict__ slot_of,
                            int* __restrict__ t1e, int* __restrict__ t1m, int* __restrict__ nt1,
                            int* __restrict__ t2e, int* __restrict__ t2m, int* __restrict__ nt2)
{
    __shared__ int cur[NEXP];
    const int tid = threadIdx.x;
    if (tid == 0) {
        int run = 0, n1 = 0, n2 = 0;
        for (int e = 0; e < NEXP; ++e) {
            offsets[e] = run; cur[e] = run;
            for (int m0 = 0; m0 < counts[e]; m0 += 128) { t1e[n1] = e; t1m[n1] = m0; ++n1; }
            for (int m0 = 0; m0 < counts[e]; m0 += 64)  { t2e[n2] = e; t2m[n2] = m0; ++n2; }
            run += counts[e];
        }
        *nt1 = n1; *nt2 = n2;
    }
    __syncthreads();
    for (int p = tid; p < 2 * NTOK; p += blockDim.x) {
        int e = tok_idx[p];
        int s = atomicAdd(&cur[e], 1);
        pair_token[s] = p >> 1;
        pair_wt[s] = tok_wt[p];
        slot_of[p] = s;
    }
}

// ---------------- GEMM1: act = silu(X@w1^T)*(X@w3^T); BM=128 BN=64, 2-deep pipe ----------------
__global__ __launch_bounds__(256, 2) void moe_gemm1(
    const float* __restrict__ x, const float* __restrict__ w1g,
    const float* __restrict__ w3g, const int* __restrict__ counts,
    const int* __restrict__ offsets, const int* __restrict__ pair_token,
    const int* __restrict__ t1e, const int* __restrict__ t1m,
    const int* __restrict__ nt1,
    __bf16* __restrict__ act)
{
    const int ty = blockIdx.y;
    if (ty >= *nt1) return;
    const int e = t1e[ty];
    const int m0 = t1m[ty];
    const int Me = counts[e];
    const int rows = min(128, Me - m0);
    const int slot0 = offsets[e] + m0;
    const int n0 = blockIdx.x * 64;

    __shared__ __align__(16) __bf16 As[2][128 * 32];
    __shared__ __align__(16) __bf16 B1s[2][64 * 32];
    __shared__ __align__(16) __bf16 B3s[2][64 * 32];

    const int tid = threadIdx.x;
    const int lane = tid & 63;
    const int wv = tid >> 6;
    const int wm = (wv >> 1) * 64;   // 2x2 waves, wave tile 64x32
    const int wn = (wv & 1) * 32;
    const int lr = lane & 15;
    const int lk = (lane >> 4) * 8;

    f32x4 acc1[4][2], acc3[4][2];
#pragma unroll
    for (int i = 0; i < 4; ++i)
#pragma unroll
        for (int j = 0; j < 2; ++j) {
            acc1[i][j] = (f32x4){0.f, 0.f, 0.f, 0.f};
            acc3[i][j] = (f32x4){0.f, 0.f, 0.f, 0.f};
        }

    const ptrdiff_t d31 = w3g - w1g;
    const float* aptr[4];
    int awof[4];
#pragma unroll
    for (int i = 0; i < 4; ++i) {           // A: 128x32 f32, 1024 float4 slots, 4/thread
        int slot = tid + i * 256;
        int r = slot >> 3;
        int c = (slot & 7) * 4;
        int rr = (r < rows) ? r : 0;
        aptr[i] = x + (size_t)pair_token[slot0 + rr] * HDIM + c;
        awof[i] = r * 32 + c;
    }
    const float* bp[2];
    int bwof[2];
#pragma unroll
    for (int i = 0; i < 2; ++i) {           // B: 64x32 f32, 512 float4 slots, 2/thread
        int slot = tid + i * 256;
        int r = slot >> 3;
        int c = (slot & 7) * 4;
        bp[i]   = w1g + ((size_t)e * FDIM + n0 + r) * HDIM + c;
        bwof[i] = r * 32 + c;
    }

    float4 a0[4], b10[2], b30[2];
    float4 a1[4], b11[2], b31[2];

#define LD1(AV, B1V, B3V, K0) do { _Pragma("unroll") \
    for (int i = 0; i < 4; ++i) AV[i] = *(const float4*)(aptr[i] + (K0)); \
    _Pragma("unroll") \
    for (int i = 0; i < 2; ++i) { B1V[i] = *(const float4*)(bp[i] + (K0)); \
                                  B3V[i] = *(const float4*)(bp[i] + d31 + (K0)); } } while (0)

#define ST1(BUF, AV, B1V, B3V) do { _Pragma("unroll") \
    for (int i = 0; i < 4; ++i) *(v4bf*)&As[BUF][awof[i]] = cvt4(AV[i]); \
    _Pragma("unroll") \
    for (int i = 0; i < 2; ++i) { *(v4bf*)&B1s[BUF][bwof[i]] = cvt4(B1V[i]); \
                                  *(v4bf*)&B3s[BUF][bwof[i]] = cvt4(B3V[i]); } } while (0)

#define CMP1(BUF) do { v8bf af[4], b1f[2], b3f[2]; _Pragma("unroll") \
    for (int i = 0; i < 4; ++i) af[i] = *(const v8bf*)&As[BUF][(wm + i * 16 + lr) * 32 + lk]; \
    _Pragma("unroll") \
    for (int i = 0; i < 2; ++i) { b1f[i] = *(const v8bf*)&B1s[BUF][(wn + i * 16 + lr) * 32 + lk]; \
                                  b3f[i] = *(const v8bf*)&B3s[BUF][(wn + i * 16 + lr) * 32 + lk]; } \
    _Pragma("unroll") \
    for (int mi = 0; mi < 4; ++mi) { _Pragma("unroll") \
        for (int ni = 0; ni < 2; ++ni) { \
            acc1[mi][ni] = __builtin_amdgcn_mfma_f32_16x16x32_bf16(af[mi], b1f[ni], acc1[mi][ni], 0, 0, 0); \
            acc3[mi][ni] = __builtin_amdgcn_mfma_f32_16x16x32_bf16(af[mi], b3f[ni], acc3[mi][ni], 0, 0, 0); } } } while (0)

    LD1(a0, b10, b30, 0);
    LD1(a1, b11, b31, 32);
    for (int k0 = 0; k0 < HDIM; k0 += 64) {
        ST1(0, a0, b10, b30);                      // waits only on set0 (vmcnt counted)
        if (k0 + 64 < HDIM) LD1(a0, b10, b30, k0 + 64);
        BAR();
        CMP1(0);
        ST1(1, a1, b11, b31);
        if (k0 + 96 < HDIM) LD1(a1, b11, b31, k0 + 96);
        BAR();
        CMP1(1);
    }
#undef LD1
#undef ST1
#undef CMP1

    const int rj = (lane >> 4) * 4;
#pragma unroll
    for (int mi = 0; mi < 4; ++mi) {
#pragma unroll
        for (int j = 0; j < 4; ++j) {
            int rm = wm + mi * 16 + rj + j;
            if (rm < rows) {
                size_t rowoff = (size_t)(slot0 + rm) * FDIM + n0 + wn;
#pragma unroll
                for (int ni = 0; ni < 2; ++ni) {
                    float h1 = acc1[mi][ni][j];
                    float h3 = acc3[mi][ni][j];
                    float sv = (h1 / (1.f + __expf(-h1))) * h3;
                    act[rowoff + ni * 16 + lr] = (__bf16)sv;
                }
            }
        }
    }
}

// ---------------- GEMM2: y = act @ w2^T; BM=64 BN=64, 2-deep pipe ----------------
__global__ __launch_bounds__(256, 4) void moe_gemm2(
    const __bf16* __restrict__ act, const float* __restrict__ w2g,
    const int* __restrict__ counts, const int* __restrict__ offsets,
    const int* __restrict__ t2e, const int* __restrict__ t2m,
    const int* __restrict__ nt2,
    float* __restrict__ y)
{
    const int ty = blockIdx.y;
    if (ty >= *nt2) return;
    const int e = t2e[ty];
    const int m0 = t2m[ty];
    const int Me = counts[e];
    const int rows = min(64, Me - m0);
    const int slot0 = offsets[e] + m0;
    const int n0 = blockIdx.x * 64;

    __shared__ __align__(16) __bf16 As[2][64 * 32];
    __shared__ __align__(16) __bf16 Bs[2][64 * 32];

    const int tid = threadIdx.x;
    const int lane = tid & 63;
    const int wv = tid >> 6;
    const int wm = (wv >> 1) * 32;   // 2x2 waves, wave tile 32x32
    const int wn = (wv & 1) * 32;
    const int lr = lane & 15;
    const int lk = (lane >> 4) * 8;

    f32x4 acc[2][2];
#pragma unroll
    for (int i = 0; i < 2; ++i)
#pragma unroll
        for (int j = 0; j < 2; ++j) acc[i][j] = (f32x4){0.f, 0.f, 0.f, 0.f};

    // A: 64x32 bf16 = 2048 elems, 8/thread (one v8bf)
    const __bf16* ap;
    int awof;
    {
        int r = tid >> 2;
        int c = (tid & 3) * 8;
        int rr = (r < rows) ? r : 0;
        ap   = act + (size_t)(slot0 + rr) * FDIM + c;
        awof = r * 32 + c;
    }
    // B: 64x32 f32, 512 float4 slots, 2/thread
    const float* bp[2];
    int bwof[2];
#pragma unroll
    for (int i = 0; i < 2; ++i) {
        int slot = tid + i * 256;
        int r = slot >> 3;
        int c = (slot & 7) * 4;
        bp[i]   = w2g + ((size_t)e * HDIM + n0 + r) * FDIM + c;
        bwof[i] = r * 32 + c;
    }

    v8bf a8_0, a8_1;
    float4 bv0[2], bv1[2];

#define LD2(A8, BV, K0) do { A8 = *(const v8bf*)(ap + (K0)); _Pragma("unroll") \
    for (int i = 0; i < 2; ++i) BV[i] = *(const float4*)(bp[i] + (K0)); } while (0)

#define ST2(BUF, A8, BV) do { *(v8bf*)&As[BUF][awof] = A8; _Pragma("unroll") \
    for (int i = 0; i < 2; ++i) *(v4bf*)&Bs[BUF][bwof[i]] = cvt4(BV[i]); } while (0)

#define CMP2(BUF) do { v8bf af[2], bf[2]; _Pragma("unroll") \
    for (int i = 0; i < 2; ++i) { af[i] = *(const v8bf*)&As[BUF][(wm + i * 16 + lr) * 32 + lk]; \
                                  bf[i] = *(const v8bf*)&Bs[BUF][(wn + i * 16 + lr) * 32 + lk]; } \
    _Pragma("unroll") \
    for (int mi = 0; mi < 2; ++mi) { _Pragma("unroll") \
        for (int ni = 0; ni < 2; ++ni) \
            acc[mi][ni] = __builtin_amdgcn_mfma_f32_16x16x32_bf16(af[mi], bf[ni], acc[mi][ni], 0, 0, 0); } } while (0)

    LD2(a8_0, bv0, 0);
    LD2(a8_1, bv1, 32);
    for (int k0 = 0; k0 < FDIM; k0 += 64) {
        ST2(0, a8_0, bv0);
        if (k0 + 64 < FDIM) LD2(a8_0, bv0, k0 + 64);
        BAR();
        CMP2(0);
        ST2(1, a8_1, bv1);
        if (k0 + 96 < FDIM) LD2(a8_1, bv1, k0 + 96);
        BAR();
        CMP2(1);
    }
#undef LD2
#undef ST2
#undef CMP2

    const int rj = (lane >> 4) * 4;
#pragma unroll
    for (int mi = 0; mi < 2; ++mi) {
#pragma unroll
        for (int j = 0; j < 4; ++j) {
            int rm = wm + mi * 16 + rj + j;
            if (rm < rows) {
                size_t rowoff = (size_t)(slot0 + rm) * HDIM + n0 + wn;
#pragma unroll
                for (int ni = 0; ni < 2; ++ni)
                    y[rowoff + ni * 16 + lr] = acc[mi][ni][j];
            }
        }
    }
}

// ---------------- combine ----------------
__global__ __launch_bounds__(256) void moe_combine(
    const float* __restrict__ y, const int* __restrict__ slot_of,
    const float* __restrict__ pair_wt, float* __restrict__ out)
{
    const int t = blockIdx.x;
    const int tid = threadIdx.x;
    const int s0 = slot_of[2 * t];
    const int s1 = slot_of[2 * t + 1];
    const float w0 = pair_wt[s0];
    const float w1 = pair_wt[s1];
    const float4 a = *(const float4*)(y + (size_t)s0 * HDIM + tid * 4);
    const float4 b = *(const float4*)(y + (size_t)s1 * HDIM + tid * 4);
    float4 o;
    o.x = w0 * a.x + w1 * b.x;
    o.y = w0 * a.y + w1 * b.y;
    o.z = w0 * a.z + w1 * b.z;
    o.w = w0 * a.w + w1 * b.w;
    *(float4*)(out + (size_t)t * HDIM + tid * 4) = o;
}

extern "C" void kernel_launch(void* const* d_in, const int* in_sizes, int n_in,
                              void* d_out, int out_size, void* d_ws, size_t ws_size,
                              hipStream_t stream) {
    const float* x   = (const float*)d_in[0];
    const float* gw  = (const float*)d_in[1];
    const float* w1  = (const float*)d_in[2];
    const float* w2  = (const float*)d_in[3];
    const float* w3  = (const float*)d_in[4];

    float* out    = (float*)d_out;
    float* logits = out + (size_t)NTOK * HDIM;

    char* ws = (char*)d_ws;
    int*    counts     = (int*)(ws + OFF_COUNTS);
    int*    offsets    = (int*)(ws + OFF_OFFSETS);
    int*    nt1        = (int*)(ws + OFF_NT1);
    int*    nt2        = (int*)(ws + OFF_NT2);
    int*    t1e        = (int*)(ws + OFF_T1E);
    int*    t1m        = (int*)(ws + OFF_T1M);
    int*    t2e        = (int*)(ws + OFF_T2E);
    int*    t2m        = (int*)(ws + OFF_T2M);
    int*    tok_idx    = (int*)(ws + OFF_TOKIDX);
    float*  tok_wt     = (float*)(ws + OFF_TOKWT);
    int*    pair_token = (int*)(ws + OFF_PAIRTOK);
    float*  pair_wt    = (float*)(ws + OFF_PAIRWT);
    int*    slot_of    = (int*)(ws + OFF_SLOTOF);
    __bf16* act        = (__bf16*)(ws + OFF_ACT);
    float*  yb         = (float*)(ws + OFF_Y);

    hipMemsetAsync(counts, 0, 64, stream);

    moe_router<<<dim3(NTOK / 4), dim3(256), 0, stream>>>(x, gw, logits, counts, tok_idx, tok_wt);
    moe_scatter<<<dim3(1), dim3(256), 0, stream>>>(counts, tok_idx, tok_wt, offsets,
                                                   pair_token, pair_wt, slot_of,
                                                   t1e, t1m, nt1, t2e, t2m, nt2);
    moe_gemm1<<<dim3(FDIM / 64, MAXT1), dim3(256), 0, stream>>>(
        x, w1, w3, counts, offsets, pair_token, t1e, t1m, nt1, act);
    moe_gemm2<<<dim3(HDIM / 64, MAXT2), dim3(256), 0, stream>>>(
        act, w2, counts, offsets, t2e, t2m, nt2, yb);
    moe_combine<<<dim3(NTOK), dim3(256), 0, stream>>>(yb, slot_of, pair_wt, out);
}